// Round 5
// baseline (237.653 us; speedup 1.0000x reference)
//
#include <hip/hip_runtime.h>
#include <hip/hip_bf16.h>

#define NB 64     // batch
#define NV 197    // visual tokens
#define NL 64     // text tokens
#define ND 768    // input dim
#define NE 256    // embed dim

typedef __attribute__((ext_vector_type(8))) short bh8;     // 8 bf16 = 4 VGPR
typedef __attribute__((ext_vector_type(16))) float f32x16; // MFMA 32x32 accum

__device__ inline ushort f2bf(float x) {
  __hip_bfloat16 h = __float2bfloat16(x);
  return *reinterpret_cast<ushort*>(&h);
}

__device__ inline bh8 cvt8(float4 a, float4 b) {
  union { bh8 v; ushort u[8]; } r;
  r.u[0] = f2bf(a.x); r.u[1] = f2bf(a.y); r.u[2] = f2bf(a.z); r.u[3] = f2bf(a.w);
  r.u[4] = f2bf(b.x); r.u[5] = f2bf(b.y); r.u[6] = f2bf(b.z); r.u[7] = f2bf(b.w);
  return r.v;
}

// ---------- Kernel 0: W transpose + fp32->bf16 ----------
// In: W[768][256] f32. Out: Wt[256][768] bf16 (n-major, contiguous k).
// Grid (48, 4). R3 BUG FIXED: write phase now emits TWO bh8 per thread
// (c0 and c0+8), covering all 64 k-columns (was: half the tile left unwritten).
__global__ __launch_bounds__(256) void wcvt_kernel(
    const float* __restrict__ W0, const float* __restrict__ W1,
    const float* __restrict__ W2, const float* __restrict__ W3,
    ushort* __restrict__ O0, ushort* __restrict__ O1,
    ushort* __restrict__ O2, ushort* __restrict__ O3) {
  const float* Win; ushort* Wout;
  switch (blockIdx.y) {
    case 0: Win = W0; Wout = O0; break;
    case 1: Win = W1; Wout = O1; break;
    case 2: Win = W2; Wout = O2; break;
    default: Win = W3; Wout = O3; break;
  }
  const int tk = blockIdx.x % 12, tn = blockIdx.x / 12;
  const int k0 = tk * 64, n0 = tn * 64;
  __shared__ ushort ts[64][72];  // [n][k], padded rows (144 B, 16B-mult)
  const int tid = threadIdx.x;
#pragma unroll
  for (int i = 0; i < 4; ++i) {
    const int kl = (tid >> 4) + i * 16;
    const int nl = (tid & 15) * 4;
    float4 v = *(const float4*)&Win[(size_t)(k0 + kl) * NE + n0 + nl];
    ts[nl + 0][kl] = f2bf(v.x);
    ts[nl + 1][kl] = f2bf(v.y);
    ts[nl + 2][kl] = f2bf(v.z);
    ts[nl + 3][kl] = f2bf(v.w);
  }
  __syncthreads();
  const int r = tid >> 2, c0 = (tid & 3) * 16;
  bh8 v0 = *(const bh8*)&ts[r][c0];
  bh8 v1 = *(const bh8*)&ts[r][c0 + 8];
  *(bh8*)&Wout[(size_t)(n0 + r) * ND + k0 + c0] = v0;
  *(bh8*)&Wout[(size_t)(n0 + r) * ND + k0 + c0 + 8] = v1;
}

// ---------- Kernel 1: unified projection (tok + cls) via MFMA ----------
// Grid 526 x 128 thr (2 waves). Block: 32 rows x 256 cols, K=768.
// A frags: fp32 X + cvt (verified R4). B frags: bh8 loads from transposed
// bf16 W (same row-major [n][k] fragment pattern sim has used since R2).
__global__ __launch_bounds__(128, 2) void proj_kernel(
    const float* __restrict__ Xv, const float* __restrict__ Xt,
    const float* __restrict__ Xcv, const float* __restrict__ Xct,
    const ushort* __restrict__ Wvt_t, const ushort* __restrict__ Wtt_t,
    const ushort* __restrict__ Wv_t, const ushort* __restrict__ Wt_t,
    const float* __restrict__ bvt, const float* __restrict__ btt,
    const float* __restrict__ bv, const float* __restrict__ bt,
    ushort* __restrict__ v_tok, ushort* __restrict__ t_tok,
    float* __restrict__ v_cls, float* __restrict__ t_cls) {
  __shared__ float ssq_lds[2][32];

  const int blk = blockIdx.x;
  const float* X; const ushort* W; const float* bias;
  ushort* outb = nullptr; float* outf = nullptr;
  int row0; bool norm;
  if (blk < 394)      { X = Xv;  W = Wvt_t; bias = bvt; outb = v_tok; row0 = blk * 32;         norm = true; }
  else if (blk < 522) { X = Xt;  W = Wtt_t; bias = btt; outb = t_tok; row0 = (blk - 394) * 32; norm = true; }
  else if (blk < 524) { X = Xcv; W = Wv_t;  bias = bv;  outf = v_cls; row0 = (blk - 522) * 32; norm = false; }
  else                { X = Xct; W = Wt_t;  bias = bt;  outf = t_cls; row0 = (blk - 524) * 32; norm = false; }

  const int tid = threadIdx.x;
  const int l = tid & 63, w = tid >> 6;
  const int lr = l & 31, hi = l >> 5;

  const float*  Arow = X + (size_t)(row0 + lr) * ND + hi * 8;
  const ushort* B0 = W + (size_t)(w * 128 + lr) * ND + hi * 8;
  const ushort* B1 = B0 + 32 * ND;
  const ushort* B2 = B0 + 64 * ND;
  const ushort* B3 = B0 + 96 * ND;

  f32x16 acc0 = {0}, acc1 = {0}, acc2 = {0}, acc3 = {0};

#pragma unroll 4
  for (int ks = 0; ks < 48; ++ks) {
    float4 a0 = *(const float4*)(Arow + ks * 16);
    float4 a1 = *(const float4*)(Arow + ks * 16 + 4);
    bh8 b0 = *(const bh8*)(B0 + ks * 16);
    bh8 b1 = *(const bh8*)(B1 + ks * 16);
    bh8 b2 = *(const bh8*)(B2 + ks * 16);
    bh8 b3 = *(const bh8*)(B3 + ks * 16);
    bh8 af = cvt8(a0, a1);
    acc0 = __builtin_amdgcn_mfma_f32_32x32x16_bf16(af, b0, acc0, 0, 0, 0);
    acc1 = __builtin_amdgcn_mfma_f32_32x32x16_bf16(af, b1, acc1, 0, 0, 0);
    acc2 = __builtin_amdgcn_mfma_f32_32x32x16_bf16(af, b2, acc2, 0, 0, 0);
    acc3 = __builtin_amdgcn_mfma_f32_32x32x16_bf16(af, b3, acc3, 0, 0, 0);
  }

  const float bn0 = bias[w * 128 + lr];
  const float bn1 = bias[w * 128 + 32 + lr];
  const float bn2 = bias[w * 128 + 64 + lr];
  const float bn3 = bias[w * 128 + 96 + lr];
#pragma unroll
  for (int r = 0; r < 16; ++r) {
    acc0[r] += bn0; acc1[r] += bn1; acc2[r] += bn2; acc3[r] += bn3;
  }

  if (norm) {
    float p[16];
#pragma unroll
    for (int r = 0; r < 16; ++r)
      p[r] = acc0[r] * acc0[r] + acc1[r] * acc1[r] +
             acc2[r] * acc2[r] + acc3[r] * acc3[r];
#pragma unroll
    for (int off = 1; off < 32; off <<= 1) {
#pragma unroll
      for (int r = 0; r < 16; ++r) p[r] += __shfl_xor(p[r], off);
    }
    if (lr == 0) {
#pragma unroll
      for (int r = 0; r < 16; ++r)
        ssq_lds[w][(r & 3) + 8 * (r >> 2) + 4 * hi] = p[r];
    }
    __syncthreads();
#pragma unroll
    for (int r = 0; r < 16; ++r) {
      const int R = (r & 3) + 8 * (r >> 2) + 4 * hi;
      const float s = ssq_lds[0][R] + ssq_lds[1][R];
      const float scale = 1.0f / fmaxf(sqrtf(s), 1e-12f);
      ushort* orow = outb + (size_t)(row0 + R) * NE + w * 128 + lr;
      orow[0]  = f2bf(acc0[r] * scale);
      orow[32] = f2bf(acc1[r] * scale);
      orow[64] = f2bf(acc2[r] * scale);
      orow[96] = f2bf(acc3[r] * scale);
    }
  } else {
#pragma unroll
    for (int r = 0; r < 16; ++r) {
      const int R = (r & 3) + 8 * (r >> 2) + 4 * hi;
      float* orow = outf + (size_t)(row0 + R) * NE + w * 128 + lr;
      orow[0]  = acc0[r];
      orow[32] = acc1[r];
      orow[64] = acc2[r];
      orow[96] = acc3[r];
    }
  }
}

// ---------- Kernel 2: chamfer similarity via bf16 MFMA ----------
// vs R2-verified: (1) A-prefetch ring continuous ACROSS b-iters (refill at
// s>=12 fetches b+1 steps 0..3 -> epilogue hides their latency),
// (2) no in-loop barriers: per-(ib,w) LDS slots, ONE __syncthreads, final
// combine parallel across waves, (3) setprio(1) around MFMA loop.
__global__ __launch_bounds__(256, 2) void sim_kernel(
    const __hip_bfloat16* __restrict__ vt,
    const __hip_bfloat16* __restrict__ tt,
    const int* __restrict__ tlen,
    float* __restrict__ out_i2t,
    float* __restrict__ out_t2i) {
  __shared__ float red[8][4][64];  // [ib][wave][t]
  __shared__ float wsum[8][4];     // [ib][wave]

  const int blk = blockIdx.x;
  const int q = blk & 63;
  const int bc = blk >> 6;
  const int tid = threadIdx.x;
  const int l = tid & 63;
  const int w = tid >> 6;
  const int lr = l & 31;
  const int hi = l >> 5;
  const size_t bstride = (size_t)NV * NE;  // elements per b in vt

  bh8 breg0[16], breg1[16];
  {
    const __hip_bfloat16* T0 = tt + ((size_t)(q * NL) + lr) * NE + hi * 8;
    const __hip_bfloat16* T1 = T0 + 32 * NE;
#pragma unroll
    for (int s = 0; s < 16; ++s) {
      breg0[s] = *(const bh8*)(T0 + s * 16);
      breg1[s] = *(const bh8*)(T1 + s * 16);
    }
  }

  const int r0 = 32 * w + lr;
  const int r1 = min(128 + 32 * w + lr, NV - 1);

  const __hip_bfloat16* A0 = vt + (size_t)(bc * 8) * bstride + (size_t)r0 * NE + hi * 8;
  const __hip_bfloat16* A1 = vt + (size_t)(bc * 8) * bstride + (size_t)r1 * NE + hi * 8;

  // initial ring fill: ib=0 steps 0..3
  bh8 a0[4], a1[4];
#pragma unroll
  for (int s = 0; s < 4; ++s) {
    a0[s] = *(const bh8*)(A0 + s * 16);
    a1[s] = *(const bh8*)(A1 + s * 16);
  }

  for (int ib = 0; ib < 8; ++ib) {
    f32x16 acc00 = {0}, acc01 = {0}, acc10 = {0}, acc11 = {0};

    __builtin_amdgcn_s_setprio(1);
#pragma unroll
    for (int s = 0; s < 16; ++s) {
      bh8 va0 = a0[s & 3], va1 = a1[s & 3];
      // refill slot with step s+4; (s+4)>=16 rolls into next b (ib=7 tail
      // reads land in t_tok region: allocated, never consumed)
      const int sn = s + 4;
      const size_t off = (size_t)(sn & 15) * 16 + (size_t)(sn >> 4) * bstride;
      a0[s & 3] = *(const bh8*)(A0 + off);
      a1[s & 3] = *(const bh8*)(A1 + off);
      acc00 = __builtin_amdgcn_mfma_f32_32x32x16_bf16(va0, breg0[s], acc00, 0, 0, 0);
      acc01 = __builtin_amdgcn_mfma_f32_32x32x16_bf16(va0, breg1[s], acc01, 0, 0, 0);
      acc10 = __builtin_amdgcn_mfma_f32_32x32x16_bf16(va1, breg0[s], acc10, 0, 0, 0);
      acc11 = __builtin_amdgcn_mfma_f32_32x32x16_bf16(va1, breg1[s], acc11, 0, 0, 0);
    }
    __builtin_amdgcn_s_setprio(0);
    A0 += bstride;
    A1 += bstride;

    // i2t: per-row max over 64 t, sum valid rows
    float i2t_sum = 0.0f;
#pragma unroll
    for (int r = 0; r < 16; ++r) {
      {
        float m = fmaxf(acc00[r], acc01[r]);
        m = fmaxf(m, __shfl_xor(m, 1));
        m = fmaxf(m, __shfl_xor(m, 2));
        m = fmaxf(m, __shfl_xor(m, 4));
        m = fmaxf(m, __shfl_xor(m, 8));
        m = fmaxf(m, __shfl_xor(m, 16));
        i2t_sum += m;
      }
      {
        float m = fmaxf(acc10[r], acc11[r]);
        m = fmaxf(m, __shfl_xor(m, 1));
        m = fmaxf(m, __shfl_xor(m, 2));
        m = fmaxf(m, __shfl_xor(m, 4));
        m = fmaxf(m, __shfl_xor(m, 8));
        m = fmaxf(m, __shfl_xor(m, 16));
        const int row = 128 + 32 * w + (r & 3) + 8 * (r >> 2) + 4 * hi;
        if (row < NV) i2t_sum += m;
      }
    }
    i2t_sum += __shfl_xor(i2t_sum, 32);
    if (l == 0) wsum[ib][w] = i2t_sum;

    // t2i: per-col max over this wave's rows
    float vm0 = -1e30f, vm1 = -1e30f;
#pragma unroll
    for (int r = 0; r < 16; ++r) {
      vm0 = fmaxf(vm0, fmaxf(acc00[r], acc10[r]));
      vm1 = fmaxf(vm1, fmaxf(acc01[r], acc11[r]));
    }
    vm0 = fmaxf(vm0, __shfl_xor(vm0, 32));
    vm1 = fmaxf(vm1, __shfl_xor(vm1, 32));
    if (hi == 0) red[ib][w][lr] = vm0;
    else         red[ib][w][32 + lr] = vm1;
  }

  __syncthreads();  // single barrier: all (ib, wave) partials visible

  // final combine: wave w handles ib = 2w, 2w+1
#pragma unroll
  for (int j = 0; j < 2; ++j) {
    const int ib = w * 2 + j;
    const int b = bc * 8 + ib;
    const int len = tlen[b];
    float m = fmaxf(fmaxf(red[ib][0][l], red[ib][1][l]),
                    fmaxf(red[ib][2][l], red[ib][3][l]));
    float v = (l < len) ? m : 0.0f;
#pragma unroll
    for (int off = 1; off < 64; off <<= 1) v += __shfl_xor(v, off);
    if (l == 0) {
      out_t2i[b * NB + q] = v / fmaxf((float)len, 1e-6f);
      out_i2t[b * NB + q] = (wsum[ib][0] + wsum[ib][1] +
                             wsum[ib][2] + wsum[ib][3]) / (float)NV;
    }
  }
}

extern "C" void kernel_launch(void* const* d_in, const int* in_sizes, int n_in,
                              void* d_out, int out_size, void* d_ws, size_t ws_size,
                              hipStream_t stream) {
  (void)in_sizes; (void)n_in; (void)out_size; (void)ws_size;
  const float* visual_cls    = (const float*)d_in[0];
  const float* textual_cls   = (const float*)d_in[1];
  const float* visual_tokens = (const float*)d_in[2];
  const float* textual_tokens= (const float*)d_in[3];
  const int*   text_length   = (const int*)d_in[4];
  const float* Wv  = (const float*)d_in[5];
  const float* bv  = (const float*)d_in[6];
  const float* Wt  = (const float*)d_in[7];
  const float* bt  = (const float*)d_in[8];
  const float* Wvt = (const float*)d_in[9];
  const float* bvt = (const float*)d_in[10];
  const float* Wtt = (const float*)d_in[11];
  const float* btt = (const float*)d_in[12];

  float* out   = (float*)d_out;
  float* v_cls = out;                       // 64*256
  float* t_cls = out + NB * NE;             // 64*256
  float* i2t   = out + 2 * NB * NE;         // 64*64
  float* t2i   = i2t + NB * NB;             // 64*64

  ushort* wsb   = (ushort*)d_ws;
  ushort* v_tok = wsb;                                  // 12608*256 bf16
  ushort* t_tok = v_tok + (size_t)NB * NV * NE;         // 4096*256 bf16
  ushort* Wvt_t = t_tok + (size_t)NB * NL * NE;         // 256*768 bf16 each
  ushort* Wtt_t = Wvt_t + (size_t)NE * ND;
  ushort* Wv_t  = Wtt_t + (size_t)NE * ND;
  ushort* Wt_t  = Wv_t  + (size_t)NE * ND;

  wcvt_kernel<<<dim3(48, 4), 256, 0, stream>>>(Wvt, Wtt, Wv, Wt,
                                               Wvt_t, Wtt_t, Wv_t, Wt_t);
  proj_kernel<<<526, 128, 0, stream>>>(visual_tokens, textual_tokens,
                                       visual_cls, textual_cls,
                                       Wvt_t, Wtt_t, Wv_t, Wt_t,
                                       bvt, btt, bv, bt,
                                       v_tok, t_tok, v_cls, t_cls);
  sim_kernel<<<NB * NB / 8, 256, 0, stream>>>((const __hip_bfloat16*)v_tok,
                                              (const __hip_bfloat16*)t_tok,
                                              text_length, i2t, t2i);
}

// Round 6
// 234.241 us; speedup vs baseline: 1.0146x; 1.0146x over previous
//
#include <hip/hip_runtime.h>
#include <hip/hip_bf16.h>

#define NB 64     // batch
#define NV 197    // visual tokens
#define NL 64     // text tokens
#define ND 768    // input dim
#define NE 256    // embed dim

typedef __attribute__((ext_vector_type(8))) short bh8;     // 8 bf16 = 4 VGPR
typedef __attribute__((ext_vector_type(16))) float f32x16; // MFMA 32x32 accum

__device__ inline ushort f2bf(float x) {
  __hip_bfloat16 h = __float2bfloat16(x);
  return *reinterpret_cast<ushort*>(&h);
}

__device__ inline bh8 cvt8(float4 a, float4 b) {
  union { bh8 v; ushort u[8]; } r;
  r.u[0] = f2bf(a.x); r.u[1] = f2bf(a.y); r.u[2] = f2bf(a.z); r.u[3] = f2bf(a.w);
  r.u[4] = f2bf(b.x); r.u[5] = f2bf(b.y); r.u[6] = f2bf(b.z); r.u[7] = f2bf(b.w);
  return r.v;
}

// ---------- Kernel 0: W -> bf16 MFMA-fragment order ----------
// In: W[768][256] f32. Out: Wf[nt(8)][ks(48)][lane(64)][e(8)] bf16 where
// frag(l,e) = W[ks*16 + (l>>5)*8 + e][nt*32 + (l&31)]  (sim-verified B layout).
// proj's B-frag load becomes base + l*16: perfectly coalesced 1KB/wave-instr.
__global__ __launch_bounds__(256) void wcvt_kernel(
    const float* __restrict__ W0, const float* __restrict__ W1,
    const float* __restrict__ W2, const float* __restrict__ W3,
    ushort* __restrict__ O0, ushort* __restrict__ O1,
    ushort* __restrict__ O2, ushort* __restrict__ O3) {
  const float* Win; ushort* Wout;
  switch (blockIdx.y) {
    case 0: Win = W0; Wout = O0; break;
    case 1: Win = W1; Wout = O1; break;
    case 2: Win = W2; Wout = O2; break;
    default: Win = W3; Wout = O3; break;
  }
  const int ks = blockIdx.x;        // 0..47
  const int t = threadIdx.x;
  const int l = t & 63;
  const int lr = l & 31, hi = l >> 5;
  const int kbase = ks * 16 + hi * 8;
#pragma unroll
  for (int i = 0; i < 2; ++i) {
    const int nt = (t >> 6) + i * 4;        // 0..7
    const int n = nt * 32 + lr;
    union { bh8 v; ushort u[8]; } f;
#pragma unroll
    for (int e = 0; e < 8; ++e)
      f.u[e] = f2bf(Win[(size_t)(kbase + e) * NE + n]);   // coalesced over lr
    *(bh8*)&Wout[(size_t)((nt * 48 + ks) * 64 + l) * 8] = f.v;  // coalesced
  }
}

// swizzled fp32 A-tile float-index: 64 rows x 64 k, row = 256B.
// XOR chunk bits by row&15: balanced 8 lanes/bank-quad for all b128 ops.
__device__ inline int aswz(int row, int cbyte) {
  return ((row * 256 + cbyte) ^ ((row & 15) << 4)) >> 2;
}

// ---------- Kernel 1: unified projection (tok + cls) via MFMA ----------
// Grid 263 x 256 thr (4 waves, 2x2). Block: M=64 rows, N=256, K=768.
// A: LDS-staged fp32 (coalesced global, swizzled b128), cvt at consume.
// B: direct coalesced 16B frag loads from Wf.
__global__ __launch_bounds__(256, 2) void proj_kernel(
    const float* __restrict__ Xv, const float* __restrict__ Xt,
    const float* __restrict__ Xcv, const float* __restrict__ Xct,
    const ushort* __restrict__ Fv, const ushort* __restrict__ Ft,
    const ushort* __restrict__ Fcv, const ushort* __restrict__ Fct,
    const float* __restrict__ bvt, const float* __restrict__ btt,
    const float* __restrict__ bv, const float* __restrict__ bt,
    ushort* __restrict__ v_tok, ushort* __restrict__ t_tok,
    float* __restrict__ v_cls, float* __restrict__ t_cls) {
  __shared__ float a_lds[64 * 64];       // 16 KB, swizzled
  __shared__ float ssq_lds[2][2][32];    // [wc][wr][row]

  const int blk = blockIdx.x;
  const float* X; const ushort* F; const float* bias;
  ushort* outb = nullptr; float* outf = nullptr;
  int row0; bool norm;
  if (blk < 197)       { X = Xv;  F = Fv;  bias = bvt; outb = v_tok; row0 = blk * 64;         norm = true; }
  else if (blk < 261)  { X = Xt;  F = Ft;  bias = btt; outb = t_tok; row0 = (blk - 197) * 64; norm = true; }
  else if (blk == 261) { X = Xcv; F = Fcv; bias = bv;  outf = v_cls; row0 = 0;                norm = false; }
  else                 { X = Xct; F = Fct; bias = bt;  outf = t_cls; row0 = 0;                norm = false; }

  const int t = threadIdx.x;
  const int l = t & 63, w = t >> 6;
  const int lr = l & 31, hi = l >> 5;
  const int wr = w & 1, wc = w >> 1;

  // staging map: thread -> (row = t>>2, 16B-chunk scq = t&3 within each 64B quad)
  const int srow = t >> 2;
  const int scq = t & 3;
  const float* Xrow = X + (size_t)(row0 + srow) * ND;

  const int arow = wr * 32 + lr;                   // A-frag row (LDS)
  const ushort* Fw = F + ((size_t)(wc * 4 * 48) * 64 + l) * 8;  // +((i*48+ks)*64)*8

  f32x16 acc0 = {0}, acc1 = {0}, acc2 = {0}, acc3 = {0};

  float4 g0, g1, g2, g3, n0, n1, n2, n3;
#define GLOAD(d0, d1, d2, d3, kc) \
  d0 = *(const float4*)(Xrow + (kc) + scq * 4); \
  d1 = *(const float4*)(Xrow + (kc) + 16 + scq * 4); \
  d2 = *(const float4*)(Xrow + (kc) + 32 + scq * 4); \
  d3 = *(const float4*)(Xrow + (kc) + 48 + scq * 4);

  GLOAD(g0, g1, g2, g3, 0)
  for (int c = 0; c < 12; ++c) {
    if (c) __syncthreads();              // protect a_lds from prior readers
    *(float4*)&a_lds[aswz(srow, scq * 16)]       = g0;
    *(float4*)&a_lds[aswz(srow, 64 + scq * 16)]  = g1;
    *(float4*)&a_lds[aswz(srow, 128 + scq * 16)] = g2;
    *(float4*)&a_lds[aswz(srow, 192 + scq * 16)] = g3;
    if (c < 11) { GLOAD(n0, n1, n2, n3, (c + 1) * 64) }  // async-stage split
    __syncthreads();

#pragma unroll
    for (int ksl = 0; ksl < 4; ++ksl) {
      const int ks = c * 4 + ksl;
      float4 af0 = *(const float4*)&a_lds[aswz(arow, ksl * 64 + hi * 32)];
      float4 af1 = *(const float4*)&a_lds[aswz(arow, ksl * 64 + hi * 32 + 16)];
      bh8 b0 = *(const bh8*)(Fw + (size_t)(0 * 48 + ks) * 64 * 8);
      bh8 b1 = *(const bh8*)(Fw + (size_t)(1 * 48 + ks) * 64 * 8);
      bh8 b2 = *(const bh8*)(Fw + (size_t)(2 * 48 + ks) * 64 * 8);
      bh8 b3 = *(const bh8*)(Fw + (size_t)(3 * 48 + ks) * 64 * 8);
      bh8 af = cvt8(af0, af1);
      acc0 = __builtin_amdgcn_mfma_f32_32x32x16_bf16(af, b0, acc0, 0, 0, 0);
      acc1 = __builtin_amdgcn_mfma_f32_32x32x16_bf16(af, b1, acc1, 0, 0, 0);
      acc2 = __builtin_amdgcn_mfma_f32_32x32x16_bf16(af, b2, acc2, 0, 0, 0);
      acc3 = __builtin_amdgcn_mfma_f32_32x32x16_bf16(af, b3, acc3, 0, 0, 0);
    }
    g0 = n0; g1 = n1; g2 = n2; g3 = n3;
  }
#undef GLOAD

  // bias per col (cols: wc*128 + i*32 + lr)
  const float bn0 = bias[wc * 128 + lr];
  const float bn1 = bias[wc * 128 + 32 + lr];
  const float bn2 = bias[wc * 128 + 64 + lr];
  const float bn3 = bias[wc * 128 + 96 + lr];
#pragma unroll
  for (int r = 0; r < 16; ++r) {
    acc0[r] += bn0; acc1[r] += bn1; acc2[r] += bn2; acc3[r] += bn3;
  }

  if (norm) {
    float p[16];
#pragma unroll
    for (int r = 0; r < 16; ++r)
      p[r] = acc0[r] * acc0[r] + acc1[r] * acc1[r] +
             acc2[r] * acc2[r] + acc3[r] * acc3[r];
#pragma unroll
    for (int off = 1; off < 32; off <<= 1) {
#pragma unroll
      for (int r = 0; r < 16; ++r) p[r] += __shfl_xor(p[r], off);
    }
    if (lr == 0) {
#pragma unroll
      for (int r = 0; r < 16; ++r)
        ssq_lds[wc][wr][(r & 3) + 8 * (r >> 2) + 4 * hi] = p[r];
    }
    __syncthreads();
#pragma unroll
    for (int r = 0; r < 16; ++r) {
      const int R = (r & 3) + 8 * (r >> 2) + 4 * hi;
      const float s = ssq_lds[0][wr][R] + ssq_lds[1][wr][R];
      const float scale = 1.0f / fmaxf(sqrtf(s), 1e-12f);
      ushort* orow = outb + (size_t)(row0 + wr * 32 + R) * NE + wc * 128 + lr;
      orow[0]  = f2bf(acc0[r] * scale);
      orow[32] = f2bf(acc1[r] * scale);
      orow[64] = f2bf(acc2[r] * scale);
      orow[96] = f2bf(acc3[r] * scale);
    }
  } else {
#pragma unroll
    for (int r = 0; r < 16; ++r) {
      const int R = (r & 3) + 8 * (r >> 2) + 4 * hi;
      float* orow = outf + (size_t)(row0 + wr * 32 + R) * NE + wc * 128 + lr;
      orow[0]  = acc0[r];
      orow[32] = acc1[r];
      orow[64] = acc2[r];
      orow[96] = acc3[r];
    }
  }
}

// ---------- Kernel 2: chamfer similarity via bf16 MFMA ----------
// R5-verified structure; now 4 b's per block (grid 1024) -> 4 blocks/CU,
// 4 waves/SIMD (VGPR 124 <= 128) for 2x latency hiding.
__global__ __launch_bounds__(256, 2) void sim_kernel(
    const __hip_bfloat16* __restrict__ vt,
    const __hip_bfloat16* __restrict__ tt,
    const int* __restrict__ tlen,
    float* __restrict__ out_i2t,
    float* __restrict__ out_t2i) {
  __shared__ float red[4][4][64];  // [ib][wave][t]
  __shared__ float wsum[4][4];     // [ib][wave]

  const int blk = blockIdx.x;
  const int q = blk & 63;
  const int bc = blk >> 6;        // 0..15, 4 b's each
  const int tid = threadIdx.x;
  const int l = tid & 63;
  const int w = tid >> 6;
  const int lr = l & 31;
  const int hi = l >> 5;
  const size_t bstride = (size_t)NV * NE;

  bh8 breg0[16], breg1[16];
  {
    const __hip_bfloat16* T0 = tt + ((size_t)(q * NL) + lr) * NE + hi * 8;
    const __hip_bfloat16* T1 = T0 + 32 * NE;
#pragma unroll
    for (int s = 0; s < 16; ++s) {
      breg0[s] = *(const bh8*)(T0 + s * 16);
      breg1[s] = *(const bh8*)(T1 + s * 16);
    }
  }

  const int r0 = 32 * w + lr;
  const int r1 = min(128 + 32 * w + lr, NV - 1);

  const __hip_bfloat16* A0 = vt + (size_t)(bc * 4) * bstride + (size_t)r0 * NE + hi * 8;
  const __hip_bfloat16* A1 = vt + (size_t)(bc * 4) * bstride + (size_t)r1 * NE + hi * 8;

  bh8 a0[4], a1[4];
#pragma unroll
  for (int s = 0; s < 4; ++s) {
    a0[s] = *(const bh8*)(A0 + s * 16);
    a1[s] = *(const bh8*)(A1 + s * 16);
  }

  for (int ib = 0; ib < 4; ++ib) {
    f32x16 acc00 = {0}, acc01 = {0}, acc10 = {0}, acc11 = {0};

    __builtin_amdgcn_s_setprio(1);
#pragma unroll
    for (int s = 0; s < 16; ++s) {
      bh8 va0 = a0[s & 3], va1 = a1[s & 3];
      // refill with step s+4; rolls into next b (tail reads land in t_tok)
      const int sn = s + 4;
      const size_t off = (size_t)(sn & 15) * 16 + (size_t)(sn >> 4) * bstride;
      a0[s & 3] = *(const bh8*)(A0 + off);
      a1[s & 3] = *(const bh8*)(A1 + off);
      acc00 = __builtin_amdgcn_mfma_f32_32x32x16_bf16(va0, breg0[s], acc00, 0, 0, 0);
      acc01 = __builtin_amdgcn_mfma_f32_32x32x16_bf16(va0, breg1[s], acc01, 0, 0, 0);
      acc10 = __builtin_amdgcn_mfma_f32_32x32x16_bf16(va1, breg0[s], acc10, 0, 0, 0);
      acc11 = __builtin_amdgcn_mfma_f32_32x32x16_bf16(va1, breg1[s], acc11, 0, 0, 0);
    }
    __builtin_amdgcn_s_setprio(0);
    A0 += bstride;
    A1 += bstride;

    float i2t_sum = 0.0f;
#pragma unroll
    for (int r = 0; r < 16; ++r) {
      {
        float m = fmaxf(acc00[r], acc01[r]);
        m = fmaxf(m, __shfl_xor(m, 1));
        m = fmaxf(m, __shfl_xor(m, 2));
        m = fmaxf(m, __shfl_xor(m, 4));
        m = fmaxf(m, __shfl_xor(m, 8));
        m = fmaxf(m, __shfl_xor(m, 16));
        i2t_sum += m;
      }
      {
        float m = fmaxf(acc10[r], acc11[r]);
        m = fmaxf(m, __shfl_xor(m, 1));
        m = fmaxf(m, __shfl_xor(m, 2));
        m = fmaxf(m, __shfl_xor(m, 4));
        m = fmaxf(m, __shfl_xor(m, 8));
        m = fmaxf(m, __shfl_xor(m, 16));
        const int row = 128 + 32 * w + (r & 3) + 8 * (r >> 2) + 4 * hi;
        if (row < NV) i2t_sum += m;
      }
    }
    i2t_sum += __shfl_xor(i2t_sum, 32);
    if (l == 0) wsum[ib][w] = i2t_sum;

    float vm0 = -1e30f, vm1 = -1e30f;
#pragma unroll
    for (int r = 0; r < 16; ++r) {
      vm0 = fmaxf(vm0, fmaxf(acc00[r], acc10[r]));
      vm1 = fmaxf(vm1, fmaxf(acc01[r], acc11[r]));
    }
    vm0 = fmaxf(vm0, __shfl_xor(vm0, 32));
    vm1 = fmaxf(vm1, __shfl_xor(vm1, 32));
    if (hi == 0) red[ib][w][lr] = vm0;
    else         red[ib][w][32 + lr] = vm1;
  }

  __syncthreads();  // single barrier: all (ib, wave) partials visible

  {
    const int ib = w;               // wave w finalizes its ib
    const int b = bc * 4 + ib;
    const int len = tlen[b];
    float m = fmaxf(fmaxf(red[ib][0][l], red[ib][1][l]),
                    fmaxf(red[ib][2][l], red[ib][3][l]));
    float v = (l < len) ? m : 0.0f;
#pragma unroll
    for (int off = 1; off < 64; off <<= 1) v += __shfl_xor(v, off);
    if (l == 0) {
      out_t2i[b * NB + q] = v / fmaxf((float)len, 1e-6f);
      out_i2t[b * NB + q] = (wsum[ib][0] + wsum[ib][1] +
                             wsum[ib][2] + wsum[ib][3]) / (float)NV;
    }
  }
}

extern "C" void kernel_launch(void* const* d_in, const int* in_sizes, int n_in,
                              void* d_out, int out_size, void* d_ws, size_t ws_size,
                              hipStream_t stream) {
  (void)in_sizes; (void)n_in; (void)out_size; (void)ws_size;
  const float* visual_cls    = (const float*)d_in[0];
  const float* textual_cls   = (const float*)d_in[1];
  const float* visual_tokens = (const float*)d_in[2];
  const float* textual_tokens= (const float*)d_in[3];
  const int*   text_length   = (const int*)d_in[4];
  const float* Wv  = (const float*)d_in[5];
  const float* bv  = (const float*)d_in[6];
  const float* Wt  = (const float*)d_in[7];
  const float* bt  = (const float*)d_in[8];
  const float* Wvt = (const float*)d_in[9];
  const float* bvt = (const float*)d_in[10];
  const float* Wtt = (const float*)d_in[11];
  const float* btt = (const float*)d_in[12];

  float* out   = (float*)d_out;
  float* v_cls = out;                       // 64*256
  float* t_cls = out + NB * NE;             // 64*256
  float* i2t   = out + 2 * NB * NE;         // 64*64
  float* t2i   = i2t + NB * NB;             // 64*64

  ushort* wsb   = (ushort*)d_ws;
  ushort* v_tok = wsb;                                  // 12608*256 bf16
  ushort* t_tok = v_tok + (size_t)NB * NV * NE;         // 4096*256 bf16
  ushort* Fv    = t_tok + (size_t)NB * NL * NE;         // 8*48*64*8 each
  ushort* Ft    = Fv + (size_t)8 * 48 * 64 * 8;
  ushort* Fcv   = Ft + (size_t)8 * 48 * 64 * 8;
  ushort* Fct   = Fcv + (size_t)8 * 48 * 64 * 8;

  wcvt_kernel<<<dim3(48, 4), 256, 0, stream>>>(Wvt, Wtt, Wv, Wt,
                                               Fv, Ft, Fcv, Fct);
  proj_kernel<<<263, 256, 0, stream>>>(visual_tokens, textual_tokens,
                                       visual_cls, textual_cls,
                                       Fv, Ft, Fcv, Fct,
                                       bvt, btt, bv, bt,
                                       v_tok, t_tok, v_cls, t_cls);
  sim_kernel<<<NB * NB / 4, 256, 0, stream>>>((const __hip_bfloat16*)v_tok,
                                              (const __hip_bfloat16*)t_tok,
                                              text_length, i2t, t2i);
}